// Round 3
// baseline (710.477 us; speedup 1.0000x reference)
//
#include <hip/hip_runtime.h>
#include <hip/hip_bf16.h>

// GCN 2-layer: h1 = relu(Ahat @ (x@W1) + b1); out = Ahat @ (h1@W2) + b2
// Ahat = D^-1/2 (A + I) D^-1/2. Pull-based aggregation over CSR built per call.
// CSR fill is a 2-phase bucketed counting sort (64 dst-nodes per bucket) to
// avoid the 16x scatter-write amplification of a flat counting-sort fill
// (R2: WRITE_SIZE 101 MB for a 6.4 MB array).

// ---- degree + scan ---------------------------------------------------------

__global__ void k_deg(const int* __restrict__ ei, int E, int* __restrict__ deg) {
    int e = blockIdx.x * blockDim.x + threadIdx.x;
    if (e < E) atomicAdd(&deg[ei[E + e]], 1);  // row 1 of edge_index = dst
}

__global__ void k_scan_block(const int* __restrict__ in, int n,
                             int* __restrict__ out /* = offs+1 */,
                             int* __restrict__ bsum) {
    __shared__ int sm[256];
    int t = threadIdx.x;
    int g = blockIdx.x * 256 + t;
    int v = (g < n) ? in[g] : 0;
    sm[t] = v;
    __syncthreads();
    for (int off = 1; off < 256; off <<= 1) {
        int u = (t >= off) ? sm[t - off] : 0;
        __syncthreads();
        sm[t] += u;
        __syncthreads();
    }
    if (g < n) out[g] = sm[t];                  // local inclusive scan
    if (t == 255) bsum[blockIdx.x] = sm[255];   // block total
}

__global__ void k_scan_bsums(int* __restrict__ bsum, int nb) {
    __shared__ int sm[256];
    int t = threadIdx.x;
    int v = (t < nb) ? bsum[t] : 0;
    sm[t] = v;
    __syncthreads();
    for (int off = 1; off < 256; off <<= 1) {
        int u = (t >= off) ? sm[t - off] : 0;
        __syncthreads();
        sm[t] += u;
        __syncthreads();
    }
    if (t < nb) bsum[t] = sm[t];                // inclusive scan of block sums
}

__global__ void k_scan_add(int* __restrict__ offs, const int* __restrict__ bsum, int n) {
    int g = blockIdx.x * 256 + threadIdx.x;
    if (g == 0) offs[0] = 0;
    if (g < n) {
        int b = g >> 8;
        if (b > 0) offs[g + 1] += bsum[b - 1];
    }
}

__global__ void k_dinv(const int* __restrict__ deg, int n, float* __restrict__ dinv) {
    int i = blockIdx.x * blockDim.x + threadIdx.x;
    if (i < n) dinv[i] = 1.0f / sqrtf((float)(deg[i] + 1));  // +1 self-loop
}

// ---- bucketed CSR fill -----------------------------------------------------
// Bucket b = 64 consecutive dst nodes; its ssrc/pair region starts at offs[b<<6].

__global__ void k_cursor(const int* __restrict__ offs, int nb, int* __restrict__ cur) {
    int b = blockIdx.x * blockDim.x + threadIdx.x;
    if (b < nb) cur[b] = offs[b << 6];
}

__global__ void k_part(const int* __restrict__ ei, int E, int* __restrict__ cur,
                       int2* __restrict__ pairs) {
    int e = blockIdx.x * blockDim.x + threadIdx.x;
    if (e < E) {
        int s = ei[e], d = ei[E + e];
        int p = atomicAdd(&cur[d >> 6], 1);   // consecutive grants -> contiguous slots
        pairs[p] = make_int2(s, d);
    }
}

__global__ __launch_bounds__(256) void k_fill2(const int2* __restrict__ pairs,
                                               const int* __restrict__ offs, int n,
                                               int* __restrict__ ssrc) {
    __shared__ int cnt[64];
    int b = blockIdx.x;
    int node0 = b << 6;
    int node1 = min(node0 + 64, n);
    if (threadIdx.x < 64) cnt[threadIdx.x] = 0;
    __syncthreads();
    int pstart = offs[node0], pend = offs[node1];
    for (int p = pstart + threadIdx.x; p < pend; p += 256) {
        int2 sd = pairs[p];
        int pos = offs[sd.y] + atomicAdd(&cnt[sd.y & 63], 1);
        ssrc[pos] = sd.x;                      // scatter confined to ~8 KB window
    }
}

// ---- GEMM: HS[n,64] = dinv[:,None] * (X[n,K] @ W[K,64]) --------------------
// Register-tiled: block(256) = 64x64 tile; thread = 4x4. dinv pre-scale fused
// into the epilogue so k_agg needs no per-edge dinv gather.

#define FMA4(A, s, wv)                                                         \
    (A).x += (s) * (wv).x; (A).y += (s) * (wv).y;                              \
    (A).z += (s) * (wv).z; (A).w += (s) * (wv).w;

template <int K>
__global__ __launch_bounds__(256) void k_gemm(const float* __restrict__ X,
                                              const float* __restrict__ W,
                                              const float* __restrict__ dinv,
                                              float* __restrict__ HS, int n) {
    __shared__ float xl[64][36];  // 64 rows x 32 k, +4 pad
    __shared__ float wl[32][64];

    const int t = threadIdx.x;
    const int tc = t & 15;   // cols tc*4 .. tc*4+3
    const int tr = t >> 4;   // rows tr*4 .. tr*4+3
    const int row0 = blockIdx.x * 64;

    float4 acc[4];
    acc[0] = acc[1] = acc[2] = acc[3] = make_float4(0.f, 0.f, 0.f, 0.f);

    for (int k0 = 0; k0 < K; k0 += 32) {
#pragma unroll
        for (int i = 0; i < 2; ++i) {
            int idx = i * 256 + t;
            int r = idx >> 3, f4 = idx & 7;
            int gr = row0 + r;
            float4 v = make_float4(0.f, 0.f, 0.f, 0.f);
            if (gr < n) v = *(const float4*)(X + (size_t)gr * K + k0 + f4 * 4);
            *(float4*)&xl[r][f4 * 4] = v;
        }
#pragma unroll
        for (int i = 0; i < 2; ++i) {
            int idx = i * 256 + t;
            int kr = idx >> 4, f4 = idx & 15;
            *(float4*)&wl[kr][f4 * 4] =
                *(const float4*)(W + (size_t)(k0 + kr) * 64 + f4 * 4);
        }
        __syncthreads();

#pragma unroll
        for (int kk = 0; kk < 32; kk += 4) {
            float4 xv0 = *(float4*)&xl[tr * 4 + 0][kk];
            float4 xv1 = *(float4*)&xl[tr * 4 + 1][kk];
            float4 xv2 = *(float4*)&xl[tr * 4 + 2][kk];
            float4 xv3 = *(float4*)&xl[tr * 4 + 3][kk];
            float4 wv0 = *(float4*)&wl[kk + 0][tc * 4];
            float4 wv1 = *(float4*)&wl[kk + 1][tc * 4];
            float4 wv2 = *(float4*)&wl[kk + 2][tc * 4];
            float4 wv3 = *(float4*)&wl[kk + 3][tc * 4];

            FMA4(acc[0], xv0.x, wv0); FMA4(acc[0], xv0.y, wv1);
            FMA4(acc[0], xv0.z, wv2); FMA4(acc[0], xv0.w, wv3);
            FMA4(acc[1], xv1.x, wv0); FMA4(acc[1], xv1.y, wv1);
            FMA4(acc[1], xv1.z, wv2); FMA4(acc[1], xv1.w, wv3);
            FMA4(acc[2], xv2.x, wv0); FMA4(acc[2], xv2.y, wv1);
            FMA4(acc[2], xv2.z, wv2); FMA4(acc[2], xv2.w, wv3);
            FMA4(acc[3], xv3.x, wv0); FMA4(acc[3], xv3.y, wv1);
            FMA4(acc[3], xv3.z, wv2); FMA4(acc[3], xv3.w, wv3);
        }
        __syncthreads();
    }

#pragma unroll
    for (int ri = 0; ri < 4; ++ri) {
        int gr = row0 + tr * 4 + ri;
        if (gr < n) {
            float dv = dinv[gr];
            float4 o = acc[ri];
            o.x *= dv; o.y *= dv; o.z *= dv; o.w *= dv;
            *(float4*)(HS + (size_t)gr * 64 + tc * 4) = o;
        }
    }
}

// ---- Aggregation: out[i] = dinv[i]*(sum_e hs[src] + hs[i]) + b -------------
// hs = dinv * h (pre-scaled). Wave per node, lane = channel. 8 loads in flight.

template <bool RELU>
__global__ void k_agg(const float* __restrict__ hs, const int* __restrict__ offs,
                      const int* __restrict__ ssrc, const float* __restrict__ dinv,
                      const float* __restrict__ bias, float* __restrict__ out, int n) {
    int wavesPerBlock = blockDim.x >> 6;
    int node = blockIdx.x * wavesPerBlock + (threadIdx.x >> 6);
    if (node >= n) return;
    int lane = threadIdx.x & 63;

    int beg = offs[node];
    int end = offs[node + 1];
    float acc = hs[(size_t)node * 64 + lane];  // self-loop term (pre-scaled)

    int p = beg;
    for (; p + 7 < end; p += 8) {
        int s0 = ssrc[p + 0], s1 = ssrc[p + 1], s2 = ssrc[p + 2], s3 = ssrc[p + 3];
        int s4 = ssrc[p + 4], s5 = ssrc[p + 5], s6 = ssrc[p + 6], s7 = ssrc[p + 7];
        float v0 = hs[(size_t)s0 * 64 + lane];
        float v1 = hs[(size_t)s1 * 64 + lane];
        float v2 = hs[(size_t)s2 * 64 + lane];
        float v3 = hs[(size_t)s3 * 64 + lane];
        float v4 = hs[(size_t)s4 * 64 + lane];
        float v5 = hs[(size_t)s5 * 64 + lane];
        float v6 = hs[(size_t)s6 * 64 + lane];
        float v7 = hs[(size_t)s7 * 64 + lane];
        acc += ((v0 + v1) + (v2 + v3)) + ((v4 + v5) + (v6 + v7));
    }
    for (; p < end; ++p) {
        int s = ssrc[p];
        acc += hs[(size_t)s * 64 + lane];
    }

    float r = dinv[node] * acc + bias[lane];
    if (RELU) r = fmaxf(r, 0.0f);
    out[(size_t)node * 64 + lane] = r;
}

// ---- launch ----------------------------------------------------------------

extern "C" void kernel_launch(void* const* d_in, const int* in_sizes, int n_in,
                              void* d_out, int out_size, void* d_ws, size_t ws_size,
                              hipStream_t stream) {
    const float* x  = (const float*)d_in[0];
    const int*   ei = (const int*)d_in[1];
    const float* W1 = (const float*)d_in[2];
    const float* b1 = (const float*)d_in[3];
    const float* W2 = (const float*)d_in[4];
    const float* b2 = (const float*)d_in[5];

    const int n = in_sizes[0] / 256;   // 50000
    const int E = in_sizes[1] / 2;     // 1600000
    const int nb = (n + 63) >> 6;      // 782 buckets

    // workspace carve-up (256B aligned)
    char* ws = (char*)d_ws;
    auto carve = [&](size_t bytes) {
        void* p = (void*)ws;
        ws += (bytes + 255) & ~(size_t)255;
        return p;
    };
    int*   deg  = (int*)carve((size_t)n * 4);
    int*   offs = (int*)carve((size_t)(n + 1) * 4);
    int*   bsum = (int*)carve(256 * 4);
    int*   cur  = (int*)carve((size_t)nb * 4);
    int*   ssrc = (int*)carve((size_t)E * 4);
    float* dinv = (float*)carve((size_t)n * 4);
    float* hA   = (float*)carve((size_t)n * 64 * 4);  // aliases pairs (dead by GEMM1)
    float* hB   = (float*)carve((size_t)n * 64 * 4);
    int2*  pairs = (int2*)hA;                          // E*8 = 12.8MB == hA size

    hipMemsetAsync(deg, 0, (size_t)n * 4, stream);

    const int nbE = (E + 255) / 256;
    const int nbN = (n + 255) / 256;   // 196 (<=256 required by k_scan_bsums)

    k_deg<<<nbE, 256, 0, stream>>>(ei, E, deg);
    k_scan_block<<<nbN, 256, 0, stream>>>(deg, n, offs + 1, bsum);
    k_scan_bsums<<<1, 256, 0, stream>>>(bsum, nbN);
    k_scan_add<<<nbN, 256, 0, stream>>>(offs, bsum, n);
    k_dinv<<<nbN, 256, 0, stream>>>(deg, n, dinv);
    k_cursor<<<(nb + 255) / 256, 256, 0, stream>>>(offs, nb, cur);
    k_part<<<nbE, 256, 0, stream>>>(ei, E, cur, pairs);
    k_fill2<<<nb, 256, 0, stream>>>(pairs, offs, n, ssrc);

    const int nbG = (n + 63) / 64;  // 782

    // layer 1: hA = dinv*(x@W1) ; hB = relu(Ahat-agg + b1)  (hA overwrites pairs)
    k_gemm<256><<<nbG, 256, 0, stream>>>(x, W1, dinv, hA, n);
    k_agg<true><<<(n + 3) / 4, 256, 0, stream>>>(hA, offs, ssrc, dinv, b1, hB, n);

    // layer 2: hA = dinv*(hB@W2) ; out = Ahat-agg + b2
    k_gemm<64><<<nbG, 256, 0, stream>>>(hB, W2, dinv, hA, n);
    k_agg<false><<<(n + 3) / 4, 256, 0, stream>>>(hA, offs, ssrc, dinv, b2,
                                                  (float*)d_out, n);
}